// Round 1
// 224.382 us; speedup vs baseline: 1.0612x; 1.0612x over previous
//
#include <hip/hip_runtime.h>
#include <hip/hip_fp16.h>

// MDLSTM 64x64 grid, B=32, I=64, O=128.
//   K1 lut:   lut[p] = cell index (i*64+j) for diagonal-packed order p
//   K2 prep:  wt[g][o][k] (f16) = -W_g[k][o] * log2(e)
//   K3 gemm:  pair-interleaved preactivations, gx~ = -(x@W+b)*log2e:
//               plane01[w][p] : dword = (f0,f1) f16 pair
//               plane23[w][p] : dword = (i,o)  f16 pair
//               plane4 [w][p] : f16   = c
//   K4 recur: one wave per w=(b,o), lane j = column j, anti-diagonal sweep.
//             Merged-rcp cell math: 8 trans ops/step (5+1 exp2, 2 rcp)
//             instead of 12; z/1+E arithmetic in packed f32 pairs.
//   K5 transpose: plane4 [w][p] f16 -> out [cell][w] f32.
// Workspace: planes 64+64+32 = 160 MiB | lut 16 KiB | wt 80 KiB.

#define P23_OFF  ((size_t)64 << 20)
#define P4_OFF   ((size_t)128 << 20)
#define GX_BYTES ((size_t)160 << 20)
#define LOG2E    1.4426950408889634f

typedef __attribute__((ext_vector_type(8))) _Float16 half8;
typedef __attribute__((ext_vector_type(2))) __fp16 fp16x2;
typedef __attribute__((ext_vector_type(4))) float f32x4;
typedef __attribute__((ext_vector_type(2))) float f32x2;

__device__ __forceinline__ unsigned pkrtz(float a, float b) {
    union { fp16x2 h; unsigned u; } c;
    c.h = __builtin_amdgcn_cvt_pkrtz(a, b);
    return c.u;
}

__device__ __forceinline__ int diag_off(int d) {
    return (d < 64) ? ((d * (d + 1)) >> 1) : (4096 - (((127 - d) * (128 - d)) >> 1));
}

__global__ __launch_bounds__(256) void lut_kernel(int* __restrict__ lut) {
    int t = blockIdx.x * 256 + threadIdx.x;   // 0..4095 = i*64+j
    int i = t >> 6, j = t & 63;
    int d = i + j;
    int jmin = (d > 63) ? (d - 63) : 0;
    lut[diag_off(d) + j - jmin] = t;
}

// wt[g][o][k] = -(W_g[k][o]) * log2e  as f16
__global__ __launch_bounds__(256) void prep_w(
    const float* __restrict__ wf, const float* __restrict__ wi,
    const float* __restrict__ wo, const float* __restrict__ wc,
    _Float16* __restrict__ wt)
{
    const int g = blockIdx.x;
    const float* W = (g == 0) ? wf : (g == 1) ? (wf + 8192)
                   : (g == 2) ? wi : (g == 3) ? wo : wc;
    const int t = threadIdx.x;
    const int o = t >> 1, k0 = (t & 1) * 32;
    _Float16 buf[32];
#pragma unroll
    for (int k = 0; k < 32; ++k)
        buf[k] = (_Float16)(-W[(k0 + k) * 128 + o] * LOG2E);
    _Float16* dst = wt + ((size_t)g * 128 + o) * 64 + k0;
#pragma unroll
    for (int q = 0; q < 4; ++q) *(half8*)(dst + q * 8) = *(half8*)(buf + q * 8);
}

// MFMA GEMM: tile 128p x 128o, K=64. grid (32 p-tiles, 32 b).
__global__ __launch_bounds__(256, 2) void gemm_kernel(
    const float* __restrict__ x, const _Float16* __restrict__ wt,
    const float* __restrict__ biasf, const float* __restrict__ biasi,
    const float* __restrict__ biaso, const float* __restrict__ biasc,
    const int* __restrict__ lut, char* __restrict__ gx)
{
    __shared__ _Float16 As[128][72];     // [p][k]
    const int t  = threadIdx.x;
    const int p0 = blockIdx.x * 128;
    const int b  = blockIdx.y;

    // stage A: x rows (via lut) -> f16, As[p][k]
    {
        int r = t >> 1, k0 = (t & 1) * 32;
        int cell = lut[p0 + r];
        const float* xr = x + ((size_t)cell * 32 + b) * 64 + k0;
#pragma unroll
        for (int it = 0; it < 4; ++it) {
            float4 v0 = *(const float4*)(xr + it * 8);
            float4 v1 = *(const float4*)(xr + it * 8 + 4);
            half8 h;
            h[0] = (_Float16)v0.x; h[1] = (_Float16)v0.y;
            h[2] = (_Float16)v0.z; h[3] = (_Float16)v0.w;
            h[4] = (_Float16)v1.x; h[5] = (_Float16)v1.y;
            h[6] = (_Float16)v1.z; h[7] = (_Float16)v1.w;
            *(half8*)&As[r][k0 + it * 8] = h;
        }
    }
    __syncthreads();

    const int lane = t & 63;
    const int wv   = __builtin_amdgcn_readfirstlane(t >> 6);
    const int m    = lane & 15;
    const int quad = lane >> 4;
    const int o0   = wv * 32 + m;       // of=0 column
    const int o1   = o0 + 16;           // of=1 column
    const size_t row0 = (size_t)(b * 128 + o0) * 4096;
    const size_t row1 = (size_t)(b * 128 + o1) * 4096;
    const int pq = p0 + quad * 4;

    // -------- pair phase: gates (ga, gb) -> packed dword plane --------
    auto pair_phase = [&](const _Float16* wga, const _Float16* wgb,
                          const float* bA, const float* bB, char* plane) {
        half8 ba0[2], ba1[2], bb0[2], bb1[2];
#pragma unroll
        for (int kh = 0; kh < 2; ++kh) {
            ba0[kh] = *(const half8*)(wga + o0 * 64 + kh * 32 + quad * 8);
            ba1[kh] = *(const half8*)(wga + o1 * 64 + kh * 32 + quad * 8);
            bb0[kh] = *(const half8*)(wgb + o0 * 64 + kh * 32 + quad * 8);
            bb1[kh] = *(const half8*)(wgb + o1 * 64 + kh * 32 + quad * 8);
        }
        f32x4 aA[8][2] = {}, aB[8][2] = {};
#pragma unroll
        for (int pf = 0; pf < 8; ++pf) {
            half8 af0 = *(const half8*)&As[pf * 16 + m][quad * 8];
            half8 af1 = *(const half8*)&As[pf * 16 + m][32 + quad * 8];
            aA[pf][0] = __builtin_amdgcn_mfma_f32_16x16x32_f16(af0, ba0[0], aA[pf][0], 0, 0, 0);
            aA[pf][0] = __builtin_amdgcn_mfma_f32_16x16x32_f16(af1, ba0[1], aA[pf][0], 0, 0, 0);
            aA[pf][1] = __builtin_amdgcn_mfma_f32_16x16x32_f16(af0, ba1[0], aA[pf][1], 0, 0, 0);
            aA[pf][1] = __builtin_amdgcn_mfma_f32_16x16x32_f16(af1, ba1[1], aA[pf][1], 0, 0, 0);
            aB[pf][0] = __builtin_amdgcn_mfma_f32_16x16x32_f16(af0, bb0[0], aB[pf][0], 0, 0, 0);
            aB[pf][0] = __builtin_amdgcn_mfma_f32_16x16x32_f16(af1, bb0[1], aB[pf][0], 0, 0, 0);
            aB[pf][1] = __builtin_amdgcn_mfma_f32_16x16x32_f16(af0, bb1[0], aB[pf][1], 0, 0, 0);
            aB[pf][1] = __builtin_amdgcn_mfma_f32_16x16x32_f16(af1, bb1[1], aB[pf][1], 0, 0, 0);
        }
        float sA0 = -bA[o0] * LOG2E, sA1 = -bA[o1] * LOG2E;
        float sB0 = -bB[o0] * LOG2E, sB1 = -bB[o1] * LOG2E;
#pragma unroll
        for (int pf = 0; pf < 8; ++pf) {
#pragma unroll
            for (int of = 0; of < 2; ++of) {
                float sa = of ? sA1 : sA0, sb = of ? sB1 : sB0;
                f32x4 va = aA[pf][of], vb = aB[pf][of];
                uint4 st;
                st.x = pkrtz(va[0] + sa, vb[0] + sb);
                st.y = pkrtz(va[1] + sa, vb[1] + sb);
                st.z = pkrtz(va[2] + sa, vb[2] + sb);
                st.w = pkrtz(va[3] + sa, vb[3] + sb);
                size_t row = of ? row1 : row0;
                *(uint4*)(plane + (row + pq + pf * 16) * 4) = st;
            }
        }
    };
    pair_phase(wt,            wt + 8192,     biasf, biasf + 128, gx);
    pair_phase(wt + 2 * 8192, wt + 3 * 8192, biasi, biaso,       gx + P23_OFF);

    // -------- single phase: gate c -> f16 plane4 --------
    {
        const _Float16* wg = wt + 4 * 8192;
        half8 b0[2], b1[2];
#pragma unroll
        for (int kh = 0; kh < 2; ++kh) {
            b0[kh] = *(const half8*)(wg + o0 * 64 + kh * 32 + quad * 8);
            b1[kh] = *(const half8*)(wg + o1 * 64 + kh * 32 + quad * 8);
        }
        f32x4 ac[8][2] = {};
#pragma unroll
        for (int pf = 0; pf < 8; ++pf) {
            half8 af0 = *(const half8*)&As[pf * 16 + m][quad * 8];
            half8 af1 = *(const half8*)&As[pf * 16 + m][32 + quad * 8];
            ac[pf][0] = __builtin_amdgcn_mfma_f32_16x16x32_f16(af0, b0[0], ac[pf][0], 0, 0, 0);
            ac[pf][0] = __builtin_amdgcn_mfma_f32_16x16x32_f16(af1, b0[1], ac[pf][0], 0, 0, 0);
            ac[pf][1] = __builtin_amdgcn_mfma_f32_16x16x32_f16(af0, b1[0], ac[pf][1], 0, 0, 0);
            ac[pf][1] = __builtin_amdgcn_mfma_f32_16x16x32_f16(af1, b1[1], ac[pf][1], 0, 0, 0);
        }
        float s0 = -biasc[o0] * LOG2E, s1 = -biasc[o1] * LOG2E;
        char* plane = gx + P4_OFF;
#pragma unroll
        for (int pf = 0; pf < 8; ++pf) {
#pragma unroll
            for (int of = 0; of < 2; ++of) {
                float sb = of ? s1 : s0;
                f32x4 v = ac[pf][of];
                uint2 st;
                st.x = pkrtz(v[0] + sb, v[1] + sb);
                st.y = pkrtz(v[2] + sb, v[3] + sb);
                size_t row = of ? row1 : row0;
                *(uint2*)(plane + (row + pq + pf * 16) * 2) = st;
            }
        }
    }
}

// recurrence: wave w = (b,o); lane j = column j; 127 anti-diagonal steps.
// planes hold z~ = -(xW+b)*log2e; u pre-scaled.
// Merged-rcp cell math (8 trans/step instead of 12):
//   a_g = 1+exp2(z_g);  s = (num*mic + mff)*rcp(mff*mic)
//     with mff=af0*af1, mic=ai*ac, num = s_up*af1 + s_left*af0
//   h = og*tanh(s) = (e2-1)*rcp(ao*(e2+1)),  e2 = exp2(min(2*log2e*s, 80))
//   (clamp needed: |s| reaches ~64; gate z~ are bounded ~±4 so the a-products
//    can't overflow and need no clamp)
__global__ __launch_bounds__(256) void recur_kernel(
    char* __restrict__ gx,
    const float* __restrict__ uf, const float* __restrict__ ui,
    const float* __restrict__ uo, const float* __restrict__ uc)
{
    const int lane = threadIdx.x & 63;
    const int w = __builtin_amdgcn_readfirstlane(blockIdx.x * 4 + (threadIdx.x >> 6));
    const int o = w & 127;

    // pair coefficients: A = (f0,f1) plane, B = (i,o) plane, scalar = c plane
    const f32x2 nAu = { -uf[o]       * LOG2E, -uf[256 + o] * LOG2E };
    const f32x2 nAl = { -uf[128 + o] * LOG2E, -uf[384 + o] * LOG2E };
    const f32x2 nBu = { -ui[o]       * LOG2E, -uo[o]       * LOG2E };
    const f32x2 nBl = { -ui[128 + o] * LOG2E, -uo[128 + o] * LOG2E };
    const float nc0 = -uc[o] * LOG2E, nc1 = -uc[128 + o] * LOG2E;

    // scalar-advanced base pointers (saddr codegen), fixed per-lane offsets
    const char* pc01 = gx + (size_t)w * 16384;
    const char* pc23 = gx + P23_OFF + (size_t)w * 16384;
    const char* pc4  = gx + P4_OFF + (size_t)w * 8192;
    char*       ps4  = gx + P4_OFF + (size_t)w * 8192;
    const int l4 = lane * 4, l2 = lane * 2;

    const int zm  = (lane == 0) ? 0 : -1;
    const int bpi = (lane - 1) * 4;

    f32x2 c01, c23, n01, n23;
    float c4, n4;

#define LD3(v01_, v23_, v4_) { \
    __half2 h01 = *(const __half2*)(pc01 + l4); \
    __half2 h23 = *(const __half2*)(pc23 + l4); \
    _Float16 h4 = *(const _Float16*)(pc4 + l2); \
    v01_ = (f32x2){ __low2float(h01), __high2float(h01) }; \
    v23_ = (f32x2){ __low2float(h23), __high2float(h23) }; \
    v4_ = (float)h4; }

    LD3(c01, c23, c4); pc01 += 4;  pc23 += 4;  pc4 += 2;   // -> diag 1
    LD3(n01, n23, n4); pc01 += 8;  pc23 += 8;  pc4 += 4;   // -> diag 2

    float s_prev = 0.f, h_prev = 0.f;

#pragma unroll 2
    for (int d = 0; d < 127; ++d) {
        f32x2 t01, t23; float t4;
        LD3(t01, t23, t4);                      // prefetch diag d+2
        int del = min(d + 3, 124 - d); del = max(del, 0);
        pc01 += del * 4; pc23 += del * 4; pc4 += del * 2;

        int slb = __builtin_amdgcn_ds_bpermute(bpi, __float_as_int(s_prev)) & zm;
        int hlb = __builtin_amdgcn_ds_bpermute(bpi, __float_as_int(h_prev)) & zm;
        float sl = __int_as_float(slb), hl = __int_as_float(hlb);

        // z preactivations as packed f32 pairs (v_pk_fma_f32)
        f32x2 hu2 = { h_prev, h_prev };
        f32x2 hl2 = { hl, hl };
        f32x2 zA = __builtin_elementwise_fma(hu2, nAu,
                     __builtin_elementwise_fma(hl2, nAl, c01));
        f32x2 zB = __builtin_elementwise_fma(hu2, nBu,
                     __builtin_elementwise_fma(hl2, nBl, c23));
        float zc = fmaf(h_prev, nc0, fmaf(hl, nc1, c4));

        f32x2 eA = { __builtin_amdgcn_exp2f(zA.x), __builtin_amdgcn_exp2f(zA.y) };
        f32x2 eB = { __builtin_amdgcn_exp2f(zB.x), __builtin_amdgcn_exp2f(zB.y) };
        float ec = __builtin_amdgcn_exp2f(zc);
        f32x2 aA = eA + 1.f;              // (1+Ef0, 1+Ef1)
        f32x2 aB = eB + 1.f;              // (1+Ei,  1+Eo)
        float acg = ec + 1.f;             //  1+Ec

        float mff  = aA.x * aA.y;
        float mic  = aB.x * acg;
        float den  = mff * mic;
        float num  = fmaf(s_prev, aA.y, sl * aA.x);
        float num2 = fmaf(num, mic, mff);
        float s    = num2 * __builtin_amdgcn_rcpf(den);

        float t2 = fminf(s * (2.f * LOG2E), 80.f);
        float e2 = __builtin_amdgcn_exp2f(t2);
        float hd = fmaf(aB.y, e2, aB.y);          // ao*(e2+1)
        float h  = (e2 - 1.f) * __builtin_amdgcn_rcpf(hd);

        bool act = (unsigned)(d - lane) < 64u;   // i = d-j in [0,64)
        if (act) *(_Float16*)(ps4 + l2) = (_Float16)s;   // dead slot, coalesced
        ps4 += min(d + 1, 126 - d) * 2;

        s_prev = act ? s : 0.f;
        h_prev = act ? h : 0.f;
        c01 = n01; c23 = n23; c4 = n4;
        n01 = t01; n23 = t23; n4 = t4;
    }
#undef LD3
}

// plane4 [w][p] f16 -> out[cell][w] f32.  Tile: 64 p x 256 w.
__global__ __launch_bounds__(256) void transpose_kernel(
    const char* __restrict__ gx, const int* __restrict__ lut,
    float* __restrict__ out)
{
    __shared__ _Float16 T[256][80];
    const _Float16* p4 = (const _Float16*)(gx + P4_OFF);
    const int t  = threadIdx.x;
    const int p0 = blockIdx.x * 64;
    const int w0 = blockIdx.y * 256;
#pragma unroll
    for (int it = 0; it < 8; ++it) {
        int wl = it * 32 + (t >> 3), pl = (t & 7) * 8;
        *(half8*)&T[wl][pl] =
            *(const half8*)(p4 + (size_t)(w0 + wl) * 4096 + p0 + pl);
    }
    __syncthreads();
    float* ob = out + w0 + t;
#pragma unroll 4
    for (int p = 0; p < 64; ++p) {
        int cell = lut[p0 + p];                 // block-uniform -> scalar load
        ob[(size_t)cell * 4096] = (float)T[t][p];
    }
}

extern "C" void kernel_launch(void* const* d_in, const int* in_sizes, int n_in,
                              void* d_out, int out_size, void* d_ws, size_t ws_size,
                              hipStream_t stream) {
    const float* x     = (const float*)d_in[0];
    const float* wf    = (const float*)d_in[1];
    const float* uf    = (const float*)d_in[2];
    const float* biasf = (const float*)d_in[3];
    const float* wi    = (const float*)d_in[4];
    const float* ui    = (const float*)d_in[5];
    const float* biasi = (const float*)d_in[6];
    const float* wo    = (const float*)d_in[7];
    const float* uo    = (const float*)d_in[8];
    const float* biaso = (const float*)d_in[9];
    const float* wc    = (const float*)d_in[10];
    const float* uc    = (const float*)d_in[11];
    const float* biasc = (const float*)d_in[12];
    float* out = (float*)d_out;

    char*     gx  = (char*)d_ws;
    int*      lut = (int*)(gx + GX_BYTES);
    _Float16* wt  = (_Float16*)((char*)lut + 16384);

    lut_kernel<<<16, 256, 0, stream>>>(lut);
    prep_w<<<5, 256, 0, stream>>>(wf, wi, wo, wc, wt);
    gemm_kernel<<<dim3(32, 32), 256, 0, stream>>>(
        x, wt, biasf, biasi, biaso, biasc, lut, gx);
    recur_kernel<<<1024, 256, 0, stream>>>(gx, uf, ui, uo, uc);
    transpose_kernel<<<dim3(64, 16), 256, 0, stream>>>(gx, lut, out);
}